// Round 5
// baseline (1631.981 us; speedup 1.0000x reference)
//
#include <hip/hip_runtime.h>
#include <hip/hip_bf16.h>

#define CH 64  // IN_C = HID_C = OUT_C = 64

// ---------- CSR build ----------

// deg histogram + per-edge rank (rank written coalesced)
__global__ void deg_rank_kernel(const int* __restrict__ dst, int* __restrict__ deg,
                                int* __restrict__ rank, int E) {
    int e = blockIdx.x * blockDim.x + threadIdx.x;
    if (e < E) rank[e] = atomicAdd(&deg[dst[e]], 1);
}

// per-block (1024) exclusive scan of rs in place; also emits dis = rsqrt(deg+1)
__global__ void scan_block_kernel(int* __restrict__ rs, int* __restrict__ bsum,
                                  float* __restrict__ dis, int n) {
    __shared__ int tmp[1024];
    int t = threadIdx.x;
    int i = blockIdx.x * 1024 + t;
    int v = (i < n) ? rs[i] : 0;
    if (i < n) dis[i] = rsqrtf((float)v + 1.0f);
    tmp[t] = v;
    __syncthreads();
    for (int off = 1; off < 1024; off <<= 1) {
        int a = (t >= off) ? tmp[t - off] : 0;
        __syncthreads();
        tmp[t] += a;
        __syncthreads();
    }
    if (i < n) rs[i] = tmp[t] - v;  // exclusive
    if (t == 1023) bsum[blockIdx.x] = tmp[1023];
}

// single-block exclusive scan of bsum (nb <= 1024)
__global__ void scan_top_kernel(int* __restrict__ bsum, int nb) {
    __shared__ int tmp[1024];
    int t = threadIdx.x;
    int v = (t < nb) ? bsum[t] : 0;
    tmp[t] = v;
    __syncthreads();
    for (int off = 1; off < 1024; off <<= 1) {
        int a = (t >= off) ? tmp[t - off] : 0;
        __syncthreads();
        tmp[t] += a;
        __syncthreads();
    }
    if (t < nb) bsum[t] = tmp[t] - v;
}

__global__ void scan_add_kernel(int* __restrict__ rs, const int* __restrict__ bsum, int n) {
    int i = blockIdx.x * blockDim.x + threadIdx.x;
    if (i < n) rs[i] += bsum[i >> 10];
}

// pre-addressed fill: no atomics; rs stays row_start
__global__ void fill_csr_kernel(const int* __restrict__ src, const int* __restrict__ dst,
                                const int* __restrict__ rs, const int* __restrict__ rank,
                                int* __restrict__ col, int E) {
    int e = blockIdx.x * blockDim.x + threadIdx.x;
    if (e < E) col[rs[dst[e]] + rank[e]] = src[e];
}

// ---------- compute ----------

__device__ inline unsigned pack_bf2(float a, float b) {
    __hip_bfloat162 t;
    t.x = __float2bfloat16(a);
    t.y = __float2bfloat16(b);
    unsigned u;
    __builtin_memcpy(&u, &t, 4);
    return u;
}

// Y[r,c] = bf16( (sum_k X[r,k] * W[k,c]) * dis[r] )
// Thread tile: 4 rows x 8 contiguous cols (32 indep acc chains).
// Per k: 2x ds_read_b128 of W feed 32 FMAs (1:16 LDS:FMA).
// Store: one dwordx4 (8 bf16) per row -> lanes 0..7 cover a dense 128B segment.
__global__ void gemm64_scaled_kernel(const float* __restrict__ X, const float* __restrict__ W,
                                     const float* __restrict__ dis,
                                     __hip_bfloat16* __restrict__ Y, int n) {
    __shared__ float Ws[CH * CH];
    {
        float4* w4 = (float4*)Ws;
        const float4* g4 = (const float4*)W;
        for (int i = threadIdx.x; i < CH * CH / 4; i += 256) w4[i] = g4[i];
    }
    __syncthreads();
    int t = threadIdx.x;
    int cbase = (t & 7) * 8;                    // 8 contiguous cols
    int r0 = blockIdx.x * 128 + (t >> 3) * 4;   // 4 rows
    if (r0 >= n) return;
    int r1 = min(r0 + 1, n - 1);
    int r2 = min(r0 + 2, n - 1);
    int r3 = min(r0 + 3, n - 1);
    const float4* p0 = (const float4*)(X + (size_t)r0 * CH);
    const float4* p1 = (const float4*)(X + (size_t)r1 * CH);
    const float4* p2 = (const float4*)(X + (size_t)r2 * CH);
    const float4* p3 = (const float4*)(X + (size_t)r3 * CH);

    float acc[4][8] = {};
#pragma unroll
    for (int k4 = 0; k4 < CH / 4; ++k4) {
        union { float4 v; float f[4]; } x0, x1, x2, x3;
        x0.v = p0[k4]; x1.v = p1[k4]; x2.v = p2[k4]; x3.v = p3[k4];
#pragma unroll
        for (int kk = 0; kk < 4; ++kk) {
            const float* wrow = &Ws[(k4 * 4 + kk) * CH + cbase];
            union { float4 v; float f[4]; } wa, wb;
            wa.v = *(const float4*)wrow;
            wb.v = *(const float4*)(wrow + 4);
            float xs0 = x0.f[kk], xs1 = x1.f[kk], xs2 = x2.f[kk], xs3 = x3.f[kk];
#pragma unroll
            for (int c = 0; c < 4; ++c) {
                acc[0][c] += xs0 * wa.f[c]; acc[0][c + 4] += xs0 * wb.f[c];
                acc[1][c] += xs1 * wa.f[c]; acc[1][c + 4] += xs1 * wb.f[c];
                acc[2][c] += xs2 * wa.f[c]; acc[2][c + 4] += xs2 * wb.f[c];
                acc[3][c] += xs3 * wa.f[c]; acc[3][c + 4] += xs3 * wb.f[c];
            }
        }
    }
#pragma unroll
    for (int j = 0; j < 4; ++j) {
        int r = r0 + j;
        if (r < n) {
            float d = dis[r];
            uint4 pk;
            pk.x = pack_bf2(acc[j][0] * d, acc[j][1] * d);
            pk.y = pack_bf2(acc[j][2] * d, acc[j][3] * d);
            pk.z = pack_bf2(acc[j][4] * d, acc[j][5] * d);
            pk.w = pack_bf2(acc[j][6] * d, acc[j][7] * d);
            *(uint4*)(Y + (size_t)r * CH + cbase) = pk;  // 16B aligned dense store
        }
    }
}

// one wave per node, lane = channel (bf16 gather, fp32 accumulate):
// out[d,c] = relu( dis[d] * (sum_{e in row d} xws[col[e],c] + xws[d,c]) + b[c] )
__global__ void gather_kernel(const __hip_bfloat16* __restrict__ xws, const int* __restrict__ col,
                              const int* __restrict__ rs, const float* __restrict__ dis,
                              const float* __restrict__ b, float* __restrict__ out,
                              int n, int E) {
    int wid = (blockIdx.x * blockDim.x + threadIdx.x) >> 6;
    int lane = threadIdx.x & 63;
    if (wid >= n) return;
    int beg = rs[wid];
    int end = (wid + 1 < n) ? rs[wid + 1] : E;
    float acc = 0.0f;
    int e = beg;
    for (; e + 3 < end; e += 4) {
        int s0 = col[e], s1 = col[e + 1], s2 = col[e + 2], s3 = col[e + 3];
        float v0 = __bfloat162float(xws[s0 * CH + lane]);
        float v1 = __bfloat162float(xws[s1 * CH + lane]);
        float v2 = __bfloat162float(xws[s2 * CH + lane]);
        float v3 = __bfloat162float(xws[s3 * CH + lane]);
        acc += v0 + v1 + v2 + v3;
    }
    for (; e < end; ++e) acc += __bfloat162float(xws[col[e] * CH + lane]);
    float d = dis[wid];
    float v = d * (acc + __bfloat162float(xws[wid * CH + lane])) + b[lane];
    out[wid * CH + lane] = fmaxf(v, 0.0f);
}

// gather + relu + per-block LN partial sums
__global__ void gather_stats_kernel(const __hip_bfloat16* __restrict__ xws,
                                    const int* __restrict__ col, const int* __restrict__ rs,
                                    const float* __restrict__ dis, const float* __restrict__ b,
                                    float* __restrict__ out, int n, int E,
                                    float* __restrict__ sums, float* __restrict__ sqs) {
    int wid = (blockIdx.x * blockDim.x + threadIdx.x) >> 6;
    int lane = threadIdx.x & 63;
    float v = 0.0f;
    if (wid < n) {
        int beg = rs[wid];
        int end = (wid + 1 < n) ? rs[wid + 1] : E;
        float acc = 0.0f;
        int e = beg;
        for (; e + 3 < end; e += 4) {
            int s0 = col[e], s1 = col[e + 1], s2 = col[e + 2], s3 = col[e + 3];
            float v0 = __bfloat162float(xws[s0 * CH + lane]);
            float v1 = __bfloat162float(xws[s1 * CH + lane]);
            float v2 = __bfloat162float(xws[s2 * CH + lane]);
            float v3 = __bfloat162float(xws[s3 * CH + lane]);
            acc += v0 + v1 + v2 + v3;
        }
        for (; e < end; ++e) acc += __bfloat162float(xws[col[e] * CH + lane]);
        float d = dis[wid];
        v = fmaxf(d * (acc + __bfloat162float(xws[wid * CH + lane])) + b[lane], 0.0f);
        out[wid * CH + lane] = v;
    }
    float s = v, sq = v * v;
#pragma unroll
    for (int off = 32; off > 0; off >>= 1) {
        s += __shfl_down(s, off, 64);
        sq += __shfl_down(sq, off, 64);
    }
    __shared__ float ls[4], lq[4];
    int w = threadIdx.x >> 6;
    if ((threadIdx.x & 63) == 0) { ls[w] = s; lq[w] = sq; }
    __syncthreads();
    if (threadIdx.x == 0) {
        sums[blockIdx.x] = ls[0] + ls[1] + ls[2] + ls[3];
        sqs[blockIdx.x] = lq[0] + lq[1] + lq[2] + lq[3];
    }
}

// single block: reduce nb partials -> {scale, offset}
__global__ void reduce_final_kernel(const float* __restrict__ sums, const float* __restrict__ sqs,
                                    int nb, float n_total, const float* __restrict__ lnw,
                                    const float* __restrict__ lnb, float* __restrict__ so) {
    float s = 0.0f, sq = 0.0f;
    for (int i = threadIdx.x; i < nb; i += 1024) { s += sums[i]; sq += sqs[i]; }
#pragma unroll
    for (int off = 32; off > 0; off >>= 1) {
        s += __shfl_down(s, off, 64);
        sq += __shfl_down(sq, off, 64);
    }
    __shared__ float ls[16], lq[16];
    int w = threadIdx.x >> 6;
    if ((threadIdx.x & 63) == 0) { ls[w] = s; lq[w] = sq; }
    __syncthreads();
    if (threadIdx.x == 0) {
        float ts = 0.0f, tq = 0.0f;
        for (int i = 0; i < 16; ++i) { ts += ls[i]; tq += lq[i]; }
        float mean = ts / n_total;
        float var = tq / n_total - mean * mean;
        float scale = rsqrtf(var + 1e-5f) * lnw[0];
        so[0] = scale;
        so[1] = lnb[0] - mean * scale;
    }
}

__global__ void norm_kernel(float* __restrict__ x, int n4, const float* __restrict__ so) {
    int i = blockIdx.x * blockDim.x + threadIdx.x;
    if (i >= n4) return;
    float scale = so[0], off = so[1];
    float4* x4 = (float4*)x;
    float4 v = x4[i];
    v.x = v.x * scale + off;
    v.y = v.y * scale + off;
    v.z = v.z * scale + off;
    v.w = v.w * scale + off;
    x4[i] = v;
}

extern "C" void kernel_launch(void* const* d_in, const int* in_sizes, int n_in,
                              void* d_out, int out_size, void* d_ws, size_t ws_size,
                              hipStream_t stream) {
    const float* X   = (const float*)d_in[0];
    const int*   edg = (const int*)d_in[1];   // [2,E]: src row then dst row
    const float* W1  = (const float*)d_in[2];
    const float* b1  = (const float*)d_in[3];
    const float* W2  = (const float*)d_in[4];
    const float* b2  = (const float*)d_in[5];
    const float* lnw = (const float*)d_in[6];
    const float* lnb = (const float*)d_in[7];
    float* out = (float*)d_out;

    const int N  = in_sizes[0] / CH;   // 100000
    const int E  = in_sizes[1] / 2;    // 1600000
    const int NC = N * CH;             // 6.4M
    const int nGatherBlk = (N * CH + 255) / 256;  // 25000

    const int* srcp = edg;
    const int* dstp = edg + E;

    // workspace layout (4B units)
    int*   rs   = (int*)d_ws;                        // N  (deg -> row_start)
    int*   rank = rs + N;                            // E
    int*   col  = rank + E;                          // E
    float* dis  = (float*)(col + E);                 // N
    __hip_bfloat16* xws = (__hip_bfloat16*)(dis + N); // NC bf16
    float* h    = (float*)(xws + NC);                // NC floats
    int*   bsum = (int*)(h + NC);                    // 1024
    float* sums = (float*)(bsum + 1024);             // nGatherBlk
    float* sqs  = sums + nGatherBlk;                 // nGatherBlk
    float* so   = sqs + nGatherBlk;                  // 2 {scale, offset}

    const int B = 256;
    const int nScanBlk = (N + 1023) / 1024;          // 98
    const int nGemmBlk = (N + 127) / 128;            // 782

    // ---- CSR build ----
    hipMemsetAsync(rs, 0, (size_t)N * sizeof(int), stream);
    deg_rank_kernel<<<(E + B - 1) / B, B, 0, stream>>>(dstp, rs, rank, E);
    scan_block_kernel<<<nScanBlk, 1024, 0, stream>>>(rs, bsum, dis, N);
    scan_top_kernel<<<1, 1024, 0, stream>>>(bsum, nScanBlk);
    scan_add_kernel<<<(N + B - 1) / B, B, 0, stream>>>(rs, bsum, N);
    fill_csr_kernel<<<(E + B - 1) / B, B, 0, stream>>>(srcp, dstp, rs, rank, col, E);
    // rs holds row_start (exclusive); row i spans [rs[i], rs[i+1]), rs[N] == E

    // ---- layer 1 ----
    gemm64_scaled_kernel<<<nGemmBlk, B, 0, stream>>>(X, W1, dis, xws, N);
    gather_kernel<<<nGatherBlk, B, 0, stream>>>(xws, col, rs, dis, b1, h, N, E);

    // ---- layer 2 (LN stats fused into gather epilogue) ----
    gemm64_scaled_kernel<<<nGemmBlk, B, 0, stream>>>(h, W2, dis, xws, N);
    gather_stats_kernel<<<nGatherBlk, B, 0, stream>>>(xws, col, rs, dis, b2, out, N, E, sums, sqs);

    // ---- graph layernorm ----
    reduce_final_kernel<<<1, 1024, 0, stream>>>(sums, sqs, nGatherBlk, (float)NC, lnw, lnb, so);
    norm_kernel<<<(NC / 4 + B - 1) / B, B, 0, stream>>>(out, NC / 4, so);
}

// Round 6
// 1628.890 us; speedup vs baseline: 1.0019x; 1.0019x over previous
//
#include <hip/hip_runtime.h>
#include <hip/hip_bf16.h>

#define CH 64  // IN_C = HID_C = OUT_C = 64

// ---------- CSR build ----------

// deg histogram + per-edge rank (rank written coalesced)
__global__ void deg_rank_kernel(const int* __restrict__ dst, int* __restrict__ deg,
                                int* __restrict__ rank, int E) {
    int e = blockIdx.x * blockDim.x + threadIdx.x;
    if (e < E) rank[e] = atomicAdd(&deg[dst[e]], 1);
}

// per-block (1024) exclusive scan of rs in place; also emits dis = rsqrt(deg+1)
__global__ void scan_block_kernel(int* __restrict__ rs, int* __restrict__ bsum,
                                  float* __restrict__ dis, int n) {
    __shared__ int tmp[1024];
    int t = threadIdx.x;
    int i = blockIdx.x * 1024 + t;
    int v = (i < n) ? rs[i] : 0;
    if (i < n) dis[i] = rsqrtf((float)v + 1.0f);
    tmp[t] = v;
    __syncthreads();
    for (int off = 1; off < 1024; off <<= 1) {
        int a = (t >= off) ? tmp[t - off] : 0;
        __syncthreads();
        tmp[t] += a;
        __syncthreads();
    }
    if (i < n) rs[i] = tmp[t] - v;  // exclusive
    if (t == 1023) bsum[blockIdx.x] = tmp[1023];
}

// single-block exclusive scan of bsum (nb <= 1024)
__global__ void scan_top_kernel(int* __restrict__ bsum, int nb) {
    __shared__ int tmp[1024];
    int t = threadIdx.x;
    int v = (t < nb) ? bsum[t] : 0;
    tmp[t] = v;
    __syncthreads();
    for (int off = 1; off < 1024; off <<= 1) {
        int a = (t >= off) ? tmp[t - off] : 0;
        __syncthreads();
        tmp[t] += a;
        __syncthreads();
    }
    if (t < nb) bsum[t] = tmp[t] - v;
}

__global__ void scan_add_kernel(int* __restrict__ rs, const int* __restrict__ bsum, int n) {
    int i = blockIdx.x * blockDim.x + threadIdx.x;
    if (i < n) rs[i] += bsum[i >> 10];
}

// pre-addressed fill: no atomics; rs stays row_start
__global__ void fill_csr_kernel(const int* __restrict__ src, const int* __restrict__ dst,
                                const int* __restrict__ rs, const int* __restrict__ rank,
                                int* __restrict__ col, int E) {
    int e = blockIdx.x * blockDim.x + threadIdx.x;
    if (e < E) col[rs[dst[e]] + rank[e]] = src[e];
}

// ---------- compute ----------

__device__ inline unsigned pack_bf2(float a, float b) {
    __hip_bfloat162 t;
    t.x = __float2bfloat16(a);
    t.y = __float2bfloat16(b);
    unsigned u;
    __builtin_memcpy(&u, &t, 4);
    return u;
}

// Y[r,c] = bf16( (sum_k X[r,k] * W[k,c]) * dis[r] )
// Thread tile: 4 rows x 8 contiguous cols (32 indep acc chains, ~90 VGPRs).
// __launch_bounds__(256,4): VGPR cap 128 -> NO SPILL (R5 regression: default
// cap 64 spilled acc[] to scratch -> 1.5 GB of HBM scratch traffic).
__global__ __launch_bounds__(256, 4)
void gemm64_scaled_kernel(const float* __restrict__ X, const float* __restrict__ W,
                          const float* __restrict__ dis,
                          __hip_bfloat16* __restrict__ Y, int n) {
    __shared__ float Ws[CH * CH];
    {
        float4* w4 = (float4*)Ws;
        const float4* g4 = (const float4*)W;
        for (int i = threadIdx.x; i < CH * CH / 4; i += 256) w4[i] = g4[i];
    }
    __syncthreads();
    int t = threadIdx.x;
    int cbase = (t & 7) * 8;                    // 8 contiguous cols
    int r0 = blockIdx.x * 128 + (t >> 3) * 4;   // 4 rows
    if (r0 >= n) return;
    int r1 = min(r0 + 1, n - 1);
    int r2 = min(r0 + 2, n - 1);
    int r3 = min(r0 + 3, n - 1);
    const float4* p0 = (const float4*)(X + (size_t)r0 * CH);
    const float4* p1 = (const float4*)(X + (size_t)r1 * CH);
    const float4* p2 = (const float4*)(X + (size_t)r2 * CH);
    const float4* p3 = (const float4*)(X + (size_t)r3 * CH);

    float acc[4][8] = {};
#pragma unroll
    for (int k4 = 0; k4 < CH / 4; ++k4) {
        union { float4 v; float f[4]; } x0, x1, x2, x3;
        x0.v = p0[k4]; x1.v = p1[k4]; x2.v = p2[k4]; x3.v = p3[k4];
#pragma unroll
        for (int kk = 0; kk < 4; ++kk) {
            const float* wrow = &Ws[(k4 * 4 + kk) * CH + cbase];
            union { float4 v; float f[4]; } wa, wb;
            wa.v = *(const float4*)wrow;
            wb.v = *(const float4*)(wrow + 4);
            float xs0 = x0.f[kk], xs1 = x1.f[kk], xs2 = x2.f[kk], xs3 = x3.f[kk];
#pragma unroll
            for (int c = 0; c < 4; ++c) {
                acc[0][c] += xs0 * wa.f[c]; acc[0][c + 4] += xs0 * wb.f[c];
                acc[1][c] += xs1 * wa.f[c]; acc[1][c + 4] += xs1 * wb.f[c];
                acc[2][c] += xs2 * wa.f[c]; acc[2][c + 4] += xs2 * wb.f[c];
                acc[3][c] += xs3 * wa.f[c]; acc[3][c + 4] += xs3 * wb.f[c];
            }
        }
    }
#pragma unroll
    for (int j = 0; j < 4; ++j) {
        int r = r0 + j;
        if (r < n) {
            float d = dis[r];
            uint4 pk;
            pk.x = pack_bf2(acc[j][0] * d, acc[j][1] * d);
            pk.y = pack_bf2(acc[j][2] * d, acc[j][3] * d);
            pk.z = pack_bf2(acc[j][4] * d, acc[j][5] * d);
            pk.w = pack_bf2(acc[j][6] * d, acc[j][7] * d);
            *(uint4*)(Y + (size_t)r * CH + cbase) = pk;  // 16B aligned dense store
        }
    }
}

// one wave per node, lane = channel (bf16 gather, fp32 accumulate):
// out[d,c] = relu( dis[d] * (sum_{e in row d} xws[col[e],c] + xws[d,c]) + b[c] )
__global__ void gather_kernel(const __hip_bfloat16* __restrict__ xws, const int* __restrict__ col,
                              const int* __restrict__ rs, const float* __restrict__ dis,
                              const float* __restrict__ b, float* __restrict__ out,
                              int n, int E) {
    int wid = (blockIdx.x * blockDim.x + threadIdx.x) >> 6;
    int lane = threadIdx.x & 63;
    if (wid >= n) return;
    int beg = rs[wid];
    int end = (wid + 1 < n) ? rs[wid + 1] : E;
    float acc = 0.0f;
    int e = beg;
    for (; e + 3 < end; e += 4) {
        int s0 = col[e], s1 = col[e + 1], s2 = col[e + 2], s3 = col[e + 3];
        float v0 = __bfloat162float(xws[s0 * CH + lane]);
        float v1 = __bfloat162float(xws[s1 * CH + lane]);
        float v2 = __bfloat162float(xws[s2 * CH + lane]);
        float v3 = __bfloat162float(xws[s3 * CH + lane]);
        acc += v0 + v1 + v2 + v3;
    }
    for (; e < end; ++e) acc += __bfloat162float(xws[col[e] * CH + lane]);
    float d = dis[wid];
    float v = d * (acc + __bfloat162float(xws[wid * CH + lane])) + b[lane];
    out[wid * CH + lane] = fmaxf(v, 0.0f);
}

// gather + relu + per-block LN partial sums
__global__ void gather_stats_kernel(const __hip_bfloat16* __restrict__ xws,
                                    const int* __restrict__ col, const int* __restrict__ rs,
                                    const float* __restrict__ dis, const float* __restrict__ b,
                                    float* __restrict__ out, int n, int E,
                                    float* __restrict__ sums, float* __restrict__ sqs) {
    int wid = (blockIdx.x * blockDim.x + threadIdx.x) >> 6;
    int lane = threadIdx.x & 63;
    float v = 0.0f;
    if (wid < n) {
        int beg = rs[wid];
        int end = (wid + 1 < n) ? rs[wid + 1] : E;
        float acc = 0.0f;
        int e = beg;
        for (; e + 3 < end; e += 4) {
            int s0 = col[e], s1 = col[e + 1], s2 = col[e + 2], s3 = col[e + 3];
            float v0 = __bfloat162float(xws[s0 * CH + lane]);
            float v1 = __bfloat162float(xws[s1 * CH + lane]);
            float v2 = __bfloat162float(xws[s2 * CH + lane]);
            float v3 = __bfloat162float(xws[s3 * CH + lane]);
            acc += v0 + v1 + v2 + v3;
        }
        for (; e < end; ++e) acc += __bfloat162float(xws[col[e] * CH + lane]);
        float d = dis[wid];
        v = fmaxf(d * (acc + __bfloat162float(xws[wid * CH + lane])) + b[lane], 0.0f);
        out[wid * CH + lane] = v;
    }
    float s = v, sq = v * v;
#pragma unroll
    for (int off = 32; off > 0; off >>= 1) {
        s += __shfl_down(s, off, 64);
        sq += __shfl_down(sq, off, 64);
    }
    __shared__ float ls[4], lq[4];
    int w = threadIdx.x >> 6;
    if ((threadIdx.x & 63) == 0) { ls[w] = s; lq[w] = sq; }
    __syncthreads();
    if (threadIdx.x == 0) {
        sums[blockIdx.x] = ls[0] + ls[1] + ls[2] + ls[3];
        sqs[blockIdx.x] = lq[0] + lq[1] + lq[2] + lq[3];
    }
}

// single block: reduce nb partials -> {scale, offset}
__global__ void reduce_final_kernel(const float* __restrict__ sums, const float* __restrict__ sqs,
                                    int nb, float n_total, const float* __restrict__ lnw,
                                    const float* __restrict__ lnb, float* __restrict__ so) {
    float s = 0.0f, sq = 0.0f;
    for (int i = threadIdx.x; i < nb; i += 1024) { s += sums[i]; sq += sqs[i]; }
#pragma unroll
    for (int off = 32; off > 0; off >>= 1) {
        s += __shfl_down(s, off, 64);
        sq += __shfl_down(sq, off, 64);
    }
    __shared__ float ls[16], lq[16];
    int w = threadIdx.x >> 6;
    if ((threadIdx.x & 63) == 0) { ls[w] = s; lq[w] = sq; }
    __syncthreads();
    if (threadIdx.x == 0) {
        float ts = 0.0f, tq = 0.0f;
        for (int i = 0; i < 16; ++i) { ts += ls[i]; tq += lq[i]; }
        float mean = ts / n_total;
        float var = tq / n_total - mean * mean;
        float scale = rsqrtf(var + 1e-5f) * lnw[0];
        so[0] = scale;
        so[1] = lnb[0] - mean * scale;
    }
}

__global__ void norm_kernel(float* __restrict__ x, int n4, const float* __restrict__ so) {
    int i = blockIdx.x * blockDim.x + threadIdx.x;
    if (i >= n4) return;
    float scale = so[0], off = so[1];
    float4* x4 = (float4*)x;
    float4 v = x4[i];
    v.x = v.x * scale + off;
    v.y = v.y * scale + off;
    v.z = v.z * scale + off;
    v.w = v.w * scale + off;
    x4[i] = v;
}

extern "C" void kernel_launch(void* const* d_in, const int* in_sizes, int n_in,
                              void* d_out, int out_size, void* d_ws, size_t ws_size,
                              hipStream_t stream) {
    const float* X   = (const float*)d_in[0];
    const int*   edg = (const int*)d_in[1];   // [2,E]: src row then dst row
    const float* W1  = (const float*)d_in[2];
    const float* b1  = (const float*)d_in[3];
    const float* W2  = (const float*)d_in[4];
    const float* b2  = (const float*)d_in[5];
    const float* lnw = (const float*)d_in[6];
    const float* lnb = (const float*)d_in[7];
    float* out = (float*)d_out;

    const int N  = in_sizes[0] / CH;   // 100000
    const int E  = in_sizes[1] / 2;    // 1600000
    const int NC = N * CH;             // 6.4M
    const int nGatherBlk = (N * CH + 255) / 256;  // 25000

    const int* srcp = edg;
    const int* dstp = edg + E;

    // workspace layout (4B units)
    int*   rs   = (int*)d_ws;                        // N  (deg -> row_start)
    int*   rank = rs + N;                            // E
    int*   col  = rank + E;                          // E
    float* dis  = (float*)(col + E);                 // N
    __hip_bfloat16* xws = (__hip_bfloat16*)(dis + N); // NC bf16
    float* h    = (float*)(xws + NC);                // NC floats
    int*   bsum = (int*)(h + NC);                    // 1024
    float* sums = (float*)(bsum + 1024);             // nGatherBlk
    float* sqs  = sums + nGatherBlk;                 // nGatherBlk
    float* so   = sqs + nGatherBlk;                  // 2 {scale, offset}

    const int B = 256;
    const int nScanBlk = (N + 1023) / 1024;          // 98
    const int nGemmBlk = (N + 127) / 128;            // 782

    // ---- CSR build ----
    hipMemsetAsync(rs, 0, (size_t)N * sizeof(int), stream);
    deg_rank_kernel<<<(E + B - 1) / B, B, 0, stream>>>(dstp, rs, rank, E);
    scan_block_kernel<<<nScanBlk, 1024, 0, stream>>>(rs, bsum, dis, N);
    scan_top_kernel<<<1, 1024, 0, stream>>>(bsum, nScanBlk);
    scan_add_kernel<<<(N + B - 1) / B, B, 0, stream>>>(rs, bsum, N);
    fill_csr_kernel<<<(E + B - 1) / B, B, 0, stream>>>(srcp, dstp, rs, rank, col, E);
    // rs holds row_start (exclusive); row i spans [rs[i], rs[i+1]), rs[N] == E

    // ---- layer 1 ----
    gemm64_scaled_kernel<<<nGemmBlk, B, 0, stream>>>(X, W1, dis, xws, N);
    gather_kernel<<<nGatherBlk, B, 0, stream>>>(xws, col, rs, dis, b1, h, N, E);

    // ---- layer 2 (LN stats fused into gather epilogue) ----
    gemm64_scaled_kernel<<<nGemmBlk, B, 0, stream>>>(h, W2, dis, xws, N);
    gather_stats_kernel<<<nGatherBlk, B, 0, stream>>>(xws, col, rs, dis, b2, out, N, E, sums, sqs);

    // ---- graph layernorm ----
    reduce_final_kernel<<<1, 1024, 0, stream>>>(sums, sqs, nGatherBlk, (float)NC, lnw, lnb, so);
    norm_kernel<<<(NC / 4 + B - 1) / B, B, 0, stream>>>(out, NC / 4, so);
}

// Round 7
// 458.852 us; speedup vs baseline: 3.5567x; 3.5499x over previous
//
#include <hip/hip_runtime.h>
#include <hip/hip_bf16.h>

#define CH 64  // IN_C = HID_C = OUT_C = 64

// ---------- CSR build ----------

// deg histogram + per-edge rank (rank written coalesced)
__global__ void deg_rank_kernel(const int* __restrict__ dst, int* __restrict__ deg,
                                int* __restrict__ rank, int E) {
    int e = blockIdx.x * blockDim.x + threadIdx.x;
    if (e < E) rank[e] = atomicAdd(&deg[dst[e]], 1);
}

// per-block (1024) exclusive scan of rs in place; also emits dis = rsqrt(deg+1)
__global__ void scan_block_kernel(int* __restrict__ rs, int* __restrict__ bsum,
                                  float* __restrict__ dis, int n) {
    __shared__ int tmp[1024];
    int t = threadIdx.x;
    int i = blockIdx.x * 1024 + t;
    int v = (i < n) ? rs[i] : 0;
    if (i < n) dis[i] = rsqrtf((float)v + 1.0f);
    tmp[t] = v;
    __syncthreads();
    for (int off = 1; off < 1024; off <<= 1) {
        int a = (t >= off) ? tmp[t - off] : 0;
        __syncthreads();
        tmp[t] += a;
        __syncthreads();
    }
    if (i < n) rs[i] = tmp[t] - v;  // exclusive
    if (t == 1023) bsum[blockIdx.x] = tmp[1023];
}

// single-block exclusive scan of bsum (nb <= 1024)
__global__ void scan_top_kernel(int* __restrict__ bsum, int nb) {
    __shared__ int tmp[1024];
    int t = threadIdx.x;
    int v = (t < nb) ? bsum[t] : 0;
    tmp[t] = v;
    __syncthreads();
    for (int off = 1; off < 1024; off <<= 1) {
        int a = (t >= off) ? tmp[t - off] : 0;
        __syncthreads();
        tmp[t] += a;
        __syncthreads();
    }
    if (t < nb) bsum[t] = tmp[t] - v;
}

__global__ void scan_add_kernel(int* __restrict__ rs, const int* __restrict__ bsum, int n) {
    int i = blockIdx.x * blockDim.x + threadIdx.x;
    if (i < n) rs[i] += bsum[i >> 10];
}

// pre-addressed fill: no atomics; rs stays row_start
__global__ void fill_csr_kernel(const int* __restrict__ src, const int* __restrict__ dst,
                                const int* __restrict__ rs, const int* __restrict__ rank,
                                int* __restrict__ col, int E) {
    int e = blockIdx.x * blockDim.x + threadIdx.x;
    if (e < E) col[rs[dst[e]] + rank[e]] = src[e];
}

// ---------- compute ----------

__device__ inline unsigned pack_bf2(float a, float b) {
    __hip_bfloat162 t;
    t.x = __float2bfloat16(a);
    t.y = __float2bfloat16(b);
    unsigned u;
    __builtin_memcpy(&u, &t, 4);
    return u;
}

// 16 named-accumulator FMA block: 2 rows (xs0, xs1) x 8 cols (wa, wb)
#define FMA16(xs0, xs1, wa, wb)                                              \
    a00 += (xs0) * (wa).x; a01 += (xs0) * (wa).y;                            \
    a02 += (xs0) * (wa).z; a03 += (xs0) * (wa).w;                            \
    a04 += (xs0) * (wb).x; a05 += (xs0) * (wb).y;                            \
    a06 += (xs0) * (wb).z; a07 += (xs0) * (wb).w;                            \
    a10 += (xs1) * (wa).x; a11 += (xs1) * (wa).y;                            \
    a12 += (xs1) * (wa).z; a13 += (xs1) * (wa).w;                            \
    a14 += (xs1) * (wb).x; a15 += (xs1) * (wb).y;                            \
    a16 += (xs1) * (wb).z; a17 += (xs1) * (wb).w;

// Y[r,c] = bf16( (sum_k X[r,k] * W[k,c]) * dis[r] )
// Thread tile: 2 rows x 8 contiguous cols. ALL NAMED SCALARS — R4/R5/R6
// regression: private arrays/unions (even unroll-constant-indexed) are not
// SROA'd by hipcc; they land in HBM scratch (~1.5 GB/dispatch observed).
// LDS: 8 distinct float4 addrs/wave x 8-lane broadcast = 32 banks, no conflict.
// Store: 8 bf16 packed to one uint4 per row -> dense 16B/lane segments.
__global__ __launch_bounds__(256)
void gemm64_scaled_kernel(const float* __restrict__ X, const float* __restrict__ W,
                          const float* __restrict__ dis,
                          __hip_bfloat16* __restrict__ Y, int n) {
    __shared__ float Ws[CH * CH];
    {
        float4* w4 = (float4*)Ws;
        const float4* g4 = (const float4*)W;
        for (int i = threadIdx.x; i < CH * CH / 4; i += 256) w4[i] = g4[i];
    }
    __syncthreads();
    int t = threadIdx.x;
    int cbase = (t & 7) * 8;                   // 8 contiguous cols
    int r0 = blockIdx.x * 64 + (t >> 3) * 2;   // 2 rows; 64 rows per block
    if (r0 >= n) return;
    int r1c = min(r0 + 1, n - 1);
    const float4* p0 = (const float4*)(X + (size_t)r0 * CH);
    const float4* p1 = (const float4*)(X + (size_t)r1c * CH);

    float a00 = 0.f, a01 = 0.f, a02 = 0.f, a03 = 0.f;
    float a04 = 0.f, a05 = 0.f, a06 = 0.f, a07 = 0.f;
    float a10 = 0.f, a11 = 0.f, a12 = 0.f, a13 = 0.f;
    float a14 = 0.f, a15 = 0.f, a16 = 0.f, a17 = 0.f;

#pragma unroll
    for (int k4 = 0; k4 < CH / 4; ++k4) {
        float4 xa = p0[k4];
        float4 xb = p1[k4];
        const float* wr = &Ws[(k4 * 4) * CH + cbase];
        float4 wa, wb;
        wa = *(const float4*)(wr);
        wb = *(const float4*)(wr + 4);
        FMA16(xa.x, xb.x, wa, wb)
        wa = *(const float4*)(wr + CH);
        wb = *(const float4*)(wr + CH + 4);
        FMA16(xa.y, xb.y, wa, wb)
        wa = *(const float4*)(wr + 2 * CH);
        wb = *(const float4*)(wr + 2 * CH + 4);
        FMA16(xa.z, xb.z, wa, wb)
        wa = *(const float4*)(wr + 3 * CH);
        wb = *(const float4*)(wr + 3 * CH + 4);
        FMA16(xa.w, xb.w, wa, wb)
    }

    float d0 = dis[r0];
    uint4 pk;
    pk.x = pack_bf2(a00 * d0, a01 * d0);
    pk.y = pack_bf2(a02 * d0, a03 * d0);
    pk.z = pack_bf2(a04 * d0, a05 * d0);
    pk.w = pack_bf2(a06 * d0, a07 * d0);
    *(uint4*)(Y + (size_t)r0 * CH + cbase) = pk;
    if (r0 + 1 < n) {
        float d1 = dis[r0 + 1];
        pk.x = pack_bf2(a10 * d1, a11 * d1);
        pk.y = pack_bf2(a12 * d1, a13 * d1);
        pk.z = pack_bf2(a14 * d1, a15 * d1);
        pk.w = pack_bf2(a16 * d1, a17 * d1);
        *(uint4*)(Y + (size_t)(r0 + 1) * CH + cbase) = pk;
    }
}

// one wave per node, lane = channel (bf16 gather, fp32 accumulate):
// out[d,c] = relu( dis[d] * (sum_{e in row d} xws[col[e],c] + xws[d,c]) + b[c] )
__global__ void gather_kernel(const __hip_bfloat16* __restrict__ xws, const int* __restrict__ col,
                              const int* __restrict__ rs, const float* __restrict__ dis,
                              const float* __restrict__ b, float* __restrict__ out,
                              int n, int E) {
    int wid = (blockIdx.x * blockDim.x + threadIdx.x) >> 6;
    int lane = threadIdx.x & 63;
    if (wid >= n) return;
    int beg = rs[wid];
    int end = (wid + 1 < n) ? rs[wid + 1] : E;
    float acc = 0.0f;
    int e = beg;
    for (; e + 3 < end; e += 4) {
        int s0 = col[e], s1 = col[e + 1], s2 = col[e + 2], s3 = col[e + 3];
        float v0 = __bfloat162float(xws[s0 * CH + lane]);
        float v1 = __bfloat162float(xws[s1 * CH + lane]);
        float v2 = __bfloat162float(xws[s2 * CH + lane]);
        float v3 = __bfloat162float(xws[s3 * CH + lane]);
        acc += v0 + v1 + v2 + v3;
    }
    for (; e < end; ++e) acc += __bfloat162float(xws[col[e] * CH + lane]);
    float d = dis[wid];
    float v = d * (acc + __bfloat162float(xws[wid * CH + lane])) + b[lane];
    out[wid * CH + lane] = fmaxf(v, 0.0f);
}

// gather + relu + per-block LN partial sums
__global__ void gather_stats_kernel(const __hip_bfloat16* __restrict__ xws,
                                    const int* __restrict__ col, const int* __restrict__ rs,
                                    const float* __restrict__ dis, const float* __restrict__ b,
                                    float* __restrict__ out, int n, int E,
                                    float* __restrict__ sums, float* __restrict__ sqs) {
    int wid = (blockIdx.x * blockDim.x + threadIdx.x) >> 6;
    int lane = threadIdx.x & 63;
    float v = 0.0f;
    if (wid < n) {
        int beg = rs[wid];
        int end = (wid + 1 < n) ? rs[wid + 1] : E;
        float acc = 0.0f;
        int e = beg;
        for (; e + 3 < end; e += 4) {
            int s0 = col[e], s1 = col[e + 1], s2 = col[e + 2], s3 = col[e + 3];
            float v0 = __bfloat162float(xws[s0 * CH + lane]);
            float v1 = __bfloat162float(xws[s1 * CH + lane]);
            float v2 = __bfloat162float(xws[s2 * CH + lane]);
            float v3 = __bfloat162float(xws[s3 * CH + lane]);
            acc += v0 + v1 + v2 + v3;
        }
        for (; e < end; ++e) acc += __bfloat162float(xws[col[e] * CH + lane]);
        float d = dis[wid];
        v = fmaxf(d * (acc + __bfloat162float(xws[wid * CH + lane])) + b[lane], 0.0f);
        out[wid * CH + lane] = v;
    }
    float s = v, sq = v * v;
#pragma unroll
    for (int off = 32; off > 0; off >>= 1) {
        s += __shfl_down(s, off, 64);
        sq += __shfl_down(sq, off, 64);
    }
    __shared__ float ls[4], lq[4];
    int w = threadIdx.x >> 6;
    if ((threadIdx.x & 63) == 0) { ls[w] = s; lq[w] = sq; }
    __syncthreads();
    if (threadIdx.x == 0) {
        sums[blockIdx.x] = ls[0] + ls[1] + ls[2] + ls[3];
        sqs[blockIdx.x] = lq[0] + lq[1] + lq[2] + lq[3];
    }
}

// single block: reduce nb partials -> {scale, offset}
__global__ void reduce_final_kernel(const float* __restrict__ sums, const float* __restrict__ sqs,
                                    int nb, float n_total, const float* __restrict__ lnw,
                                    const float* __restrict__ lnb, float* __restrict__ so) {
    float s = 0.0f, sq = 0.0f;
    for (int i = threadIdx.x; i < nb; i += 1024) { s += sums[i]; sq += sqs[i]; }
#pragma unroll
    for (int off = 32; off > 0; off >>= 1) {
        s += __shfl_down(s, off, 64);
        sq += __shfl_down(sq, off, 64);
    }
    __shared__ float ls[16], lq[16];
    int w = threadIdx.x >> 6;
    if ((threadIdx.x & 63) == 0) { ls[w] = s; lq[w] = sq; }
    __syncthreads();
    if (threadIdx.x == 0) {
        float ts = 0.0f, tq = 0.0f;
        for (int i = 0; i < 16; ++i) { ts += ls[i]; tq += lq[i]; }
        float mean = ts / n_total;
        float var = tq / n_total - mean * mean;
        float scale = rsqrtf(var + 1e-5f) * lnw[0];
        so[0] = scale;
        so[1] = lnb[0] - mean * scale;
    }
}

__global__ void norm_kernel(float* __restrict__ x, int n4, const float* __restrict__ so) {
    int i = blockIdx.x * blockDim.x + threadIdx.x;
    if (i >= n4) return;
    float scale = so[0], off = so[1];
    float4* x4 = (float4*)x;
    float4 v = x4[i];
    v.x = v.x * scale + off;
    v.y = v.y * scale + off;
    v.z = v.z * scale + off;
    v.w = v.w * scale + off;
    x4[i] = v;
}

extern "C" void kernel_launch(void* const* d_in, const int* in_sizes, int n_in,
                              void* d_out, int out_size, void* d_ws, size_t ws_size,
                              hipStream_t stream) {
    const float* X   = (const float*)d_in[0];
    const int*   edg = (const int*)d_in[1];   // [2,E]: src row then dst row
    const float* W1  = (const float*)d_in[2];
    const float* b1  = (const float*)d_in[3];
    const float* W2  = (const float*)d_in[4];
    const float* b2  = (const float*)d_in[5];
    const float* lnw = (const float*)d_in[6];
    const float* lnb = (const float*)d_in[7];
    float* out = (float*)d_out;

    const int N  = in_sizes[0] / CH;   // 100000
    const int E  = in_sizes[1] / 2;    // 1600000
    const int NC = N * CH;             // 6.4M
    const int nGatherBlk = (N * CH + 255) / 256;  // 25000

    const int* srcp = edg;
    const int* dstp = edg + E;

    // workspace layout (4B units)
    int*   rs   = (int*)d_ws;                        // N  (deg -> row_start)
    int*   rank = rs + N;                            // E
    int*   col  = rank + E;                          // E
    float* dis  = (float*)(col + E);                 // N
    __hip_bfloat16* xws = (__hip_bfloat16*)(dis + N); // NC bf16
    float* h    = (float*)(xws + NC);                // NC floats
    int*   bsum = (int*)(h + NC);                    // 1024
    float* sums = (float*)(bsum + 1024);             // nGatherBlk
    float* sqs  = sums + nGatherBlk;                 // nGatherBlk
    float* so   = sqs + nGatherBlk;                  // 2 {scale, offset}

    const int B = 256;
    const int nScanBlk = (N + 1023) / 1024;          // 98
    const int nGemmBlk = (N + 63) / 64;              // 1563

    // ---- CSR build ----
    hipMemsetAsync(rs, 0, (size_t)N * sizeof(int), stream);
    deg_rank_kernel<<<(E + B - 1) / B, B, 0, stream>>>(dstp, rs, rank, E);
    scan_block_kernel<<<nScanBlk, 1024, 0, stream>>>(rs, bsum, dis, N);
    scan_top_kernel<<<1, 1024, 0, stream>>>(bsum, nScanBlk);
    scan_add_kernel<<<(N + B - 1) / B, B, 0, stream>>>(rs, bsum, N);
    fill_csr_kernel<<<(E + B - 1) / B, B, 0, stream>>>(srcp, dstp, rs, rank, col, E);
    // rs holds row_start (exclusive); row i spans [rs[i], rs[i+1]), rs[N] == E

    // ---- layer 1 ----
    gemm64_scaled_kernel<<<nGemmBlk, B, 0, stream>>>(X, W1, dis, xws, N);
    gather_kernel<<<nGatherBlk, B, 0, stream>>>(xws, col, rs, dis, b1, h, N, E);

    // ---- layer 2 (LN stats fused into gather epilogue) ----
    gemm64_scaled_kernel<<<nGemmBlk, B, 0, stream>>>(h, W2, dis, xws, N);
    gather_stats_kernel<<<nGatherBlk, B, 0, stream>>>(xws, col, rs, dis, b2, out, N, E, sums, sqs);

    // ---- graph layernorm ----
    reduce_final_kernel<<<1, 1024, 0, stream>>>(sums, sqs, nGatherBlk, (float)NC, lnw, lnb, so);
    norm_kernel<<<(NC / 4 + B - 1) / B, B, 0, stream>>>(out, NC / 4, so);
}